// Round 1
// baseline (625.077 us; speedup 1.0000x reference)
//
#include <hip/hip_runtime.h>

// B,T,D_IN,H,LAT = 256,512,32,128,64.
// R12: MFMA matvec (16x column-redundant, ~776 cyc/step of matrix pipe) replaced
// by VALU v_dot2_f32_f16: lane = (unit u = tid>>2, K-chunk kc = tid&3), quad DPP
// butterfly reduce, per-lane gate activation, quad_perm gather to i-lane.
#define NB   256
#define NT   512
#define NDIN 32
#define NH   128
#define NLAT 64
#define HSTR 136   // hist row stride (f16): 272B rows, b128-aligned

typedef float    f32x4 __attribute__((ext_vector_type(4)));
typedef _Float16 h2    __attribute__((ext_vector_type(2)));
typedef _Float16 h4    __attribute__((ext_vector_type(4)));

__device__ __forceinline__ float dot2(h2 a, h2 b, float c) {
  return __builtin_amdgcn_fdot2(a, b, c, false);
}
__device__ __forceinline__ h2 bc2(float v) { return __builtin_bit_cast(h2, v); }
__device__ __forceinline__ h2 pk2(float a, float b) { return h2{(_Float16)a, (_Float16)b}; }

#define NLOG2E 1.44269504f
__device__ __forceinline__ float tanh_f(float x) {
  float s = __builtin_amdgcn_rcpf(1.f + __builtin_amdgcn_exp2f(x * (-2.f * NLOG2E)));
  return fmaf(2.f, s, -1.f);
}

// DPP quad_perm: ctrl bits [1:0]=src for lane0, [3:2]=lane1, [5:4]=lane2, [7:6]=lane3.
template <int CTRL>
__device__ __forceinline__ float dpp_mov(float v) {
  int p = __builtin_amdgcn_update_dpp(0, __builtin_bit_cast(int, v),
                                      CTRL, 0xF, 0xF, true);
  return __builtin_bit_cast(float, p);
}
#define QXOR1 0xB1   // [1,0,3,2]  butterfly xor-1
#define QXOR2 0x4E   // [2,3,0,1]  butterfly xor-2
#define QP1   0x39   // [1,2,3,0]  dst[p] = src[p+1]  (f -> i-lane)
#define QP2   0x4E   // [2,3,0,1]  dst[p] = src[p+2]  (g -> i-lane)
#define QP3   0x93   // [3,0,1,2]  dst[p] = src[p+3]  (o -> i-lane)
template <int CTRL>
__device__ __forceinline__ float qadd(float v) { return v + dpp_mov<CTRL>(v); }

__global__ __launch_bounds__(512, 1) void lstm_ae_kernel(
    const float* __restrict__ x,      // [B][T][D_IN]
    const float* __restrict__ eWih,   // [4H][D_IN]
    const float* __restrict__ eWhh,   // [4H][H]
    const float* __restrict__ eBih,   // [4H]
    const float* __restrict__ eBhh,   // [4H]
    const float* __restrict__ eWl,    // [LAT][H]
    const float* __restrict__ eBl,    // [LAT]
    const float* __restrict__ dWih,   // [4H][LAT]
    const float* __restrict__ dWhh,   // [4H][H]
    const float* __restrict__ dBih,   // [4H]
    const float* __restrict__ dBhh,   // [4H]
    const float* __restrict__ dWl,    // [D_IN][H]
    const float* __restrict__ dBl,    // [D_IN]
    float* __restrict__ outE,         // [B][LAT]
    float* __restrict__ outD)         // [B][T][D_IN]
{
  extern __shared__ __align__(16) char smem[];
  float*    encs = (float*)smem;                 // [64] latent
  _Float16* hs   = (_Float16*)(encs + NLAT);     // [2][128] h double-buffer
  _Float16* hist = hs + 2 * NH;                  // [512][HSTR]
  _Float16* xs   = hist;                         // alias: [512][32] encoder x
  float*    gtmp = (float*)(hist + NT * HSTR);   // [512] dec input projection

  const int tid = threadIdx.x;
  const int b   = blockIdx.x;
  const int u   = tid >> 2;      // unit 0..127
  const int kc  = tid & 3;       // K-chunk AND gate index (i,f,g,o)
  const bool writer = (kc == 0); // i-lane owns c/h of unit u
  const bool k0 = (kc & 1) != 0;
  const bool k1 = (kc & 2) != 0;
  const bool gth = (kc == 2);                          // tanh gate
  const float km = gth ? (-2.f * NLOG2E) : -NLOG2E;    // pre-scale
  const float pa = gth ? 2.f : 1.f;                    // post fixup a*s+b
  const float pb = gth ? -1.f : 0.f;

  // ---- stage x -> f16 LDS ----
  {
    const float4* xg = (const float4*)(x + (size_t)b * (NT * NDIN));
    h4* xo = (h4*)xs;
#pragma unroll
    for (int i = 0; i < 8; ++i) {
      int idx = i * 512 + tid;
      float4 v = xg[idx];
      xo[idx] = h4{(_Float16)v.x, (_Float16)v.y, (_Float16)v.z, (_Float16)v.w};
    }
  }

  // ---- per-lane weight slices (f16 in VGPRs) ----
  // ew[g*16 + j]: eWhh[g*NH+u][32*kc .. 32*kc+31] as 16 h2 per gate.
  // ewih[g*4 + j]: eWih[g*NH+u][8*kc .. 8*kc+7] as 4 h2 per gate.
  h2 ew[64], dw[64], ewih[16];
  float binit[4];
#pragma unroll
  for (int g = 0; g < 4; ++g) {
    const int r = g * NH + u;
    const float4* p = (const float4*)(eWhh + (size_t)r * NH + 32 * kc);
#pragma unroll
    for (int j = 0; j < 8; ++j) {
      float4 v = p[j];
      ew[g * 16 + 2 * j]     = pk2(v.x, v.y);
      ew[g * 16 + 2 * j + 1] = pk2(v.z, v.w);
    }
    const float4* q = (const float4*)(eWih + (size_t)r * NDIN + 8 * kc);
    float4 v0 = q[0], v1 = q[1];
    ewih[g * 4 + 0] = pk2(v0.x, v0.y);
    ewih[g * 4 + 1] = pk2(v0.z, v0.w);
    ewih[g * 4 + 2] = pk2(v1.x, v1.y);
    ewih[g * 4 + 3] = pk2(v1.z, v1.w);
    float bsum = eBih[r] + eBhh[r];
    binit[g] = writer ? bsum : 0.f;   // bias added exactly once per gate
  }
  if (tid < 2 * NH) hs[tid] = (_Float16)0.f;
  float c = 0.f;   // meaningful only on writer lanes
  __syncthreads();

  // ============================ ENCODER ============================
#pragma unroll 1
  for (int t = 0; t < NT; ++t) {
    const float4* hp = (const float4*)(hs + (t & 1) * NH + 32 * kc);
    float4 h0 = hp[0], h1 = hp[1], h2v = hp[2], h3 = hp[3];
    float4 xv = *(const float4*)(xs + t * NDIN + 8 * kc);
    float zz[4];
#pragma unroll
    for (int g = 0; g < 4; ++g) {
      float A = binit[g];
      A = dot2(ew[g * 16 +  0], bc2(h0.x), A);
      A = dot2(ew[g * 16 +  1], bc2(h0.y), A);
      A = dot2(ew[g * 16 +  2], bc2(h0.z), A);
      A = dot2(ew[g * 16 +  3], bc2(h0.w), A);
      A = dot2(ew[g * 16 +  4], bc2(h1.x), A);
      A = dot2(ew[g * 16 +  5], bc2(h1.y), A);
      A = dot2(ew[g * 16 +  6], bc2(h1.z), A);
      A = dot2(ew[g * 16 +  7], bc2(h1.w), A);
      A = dot2(ew[g * 16 +  8], bc2(h2v.x), A);
      A = dot2(ew[g * 16 +  9], bc2(h2v.y), A);
      A = dot2(ew[g * 16 + 10], bc2(h2v.z), A);
      A = dot2(ew[g * 16 + 11], bc2(h2v.w), A);
      A = dot2(ew[g * 16 + 12], bc2(h3.x), A);
      A = dot2(ew[g * 16 + 13], bc2(h3.y), A);
      A = dot2(ew[g * 16 + 14], bc2(h3.z), A);
      A = dot2(ew[g * 16 + 15], bc2(h3.w), A);
      A = dot2(ewih[g * 4 + 0], bc2(xv.x), A);
      A = dot2(ewih[g * 4 + 1], bc2(xv.y), A);
      A = dot2(ewih[g * 4 + 2], bc2(xv.z), A);
      A = dot2(ewih[g * 4 + 3], bc2(xv.w), A);
      A = qadd<QXOR1>(A);   // sum partials across the quad
      A = qadd<QXOR2>(A);   // all 4 lanes now hold full z of gate g
      zz[g] = A;
    }
    // this lane activates gate kc
    float zl = k0 ? zz[1] : zz[0];
    float zh = k0 ? zz[3] : zz[2];
    float z  = k1 ? zh : zl;
    float a  = fmaf(pa, __builtin_amdgcn_rcpf(1.f + __builtin_amdgcn_exp2f(z * km)), pb);
    // gather f,g,o into the i-lane (kc==0)
    float vf = dpp_mov<QP1>(a);
    float vg = dpp_mov<QP2>(a);
    float vo = dpp_mov<QP3>(a);
    c = fmaf(vf, c, a * vg);          // a == i on writer lanes
    float h = vo * tanh_f(c);
    if (writer) hs[((t + 1) & 1) * NH + u] = (_Float16)h;
    __syncthreads();
  }

  // ==================== LATENT + DECODER SETUP ====================
  // h_last in hs buffer 0 (t=511 wrote (512&1)=0)
  if (tid < NLAT) {
    const float4* p  = (const float4*)(eWl + (size_t)tid * NH);
    const float2* hh = (const float2*)hs;
    float a = eBl[tid];
#pragma unroll
    for (int r = 0; r < 32; ++r) {
      float4 wv = p[r];
      float2 hp = hh[r];
      h2 lov = bc2(hp.x), hiv = bc2(hp.y);
      a = fmaf((float)lov.x, wv.x, a); a = fmaf((float)lov.y, wv.y, a);
      a = fmaf((float)hiv.x, wv.z, a); a = fmaf((float)hiv.y, wv.w, a);
    }
    encs[tid] = a;
    outE[b * NLAT + tid] = a;
  }
  // decoder Whh slices (ew live range ends above; registers reuse)
#pragma unroll
  for (int g = 0; g < 4; ++g) {
    const int r = g * NH + u;
    const float4* p = (const float4*)(dWhh + (size_t)r * NH + 32 * kc);
#pragma unroll
    for (int j = 0; j < 8; ++j) {
      float4 v = p[j];
      dw[g * 16 + 2 * j]     = pk2(v.x, v.y);
      dw[g * 16 + 2 * j + 1] = pk2(v.z, v.w);
    }
  }
  __syncthreads();   // latent's hs reads done; encs published

  if (tid < 2 * NH) hs[tid] = (_Float16)0.f;
  // decoder time-invariant input projection: gtmp[r] = enc@dWih[r] + biases
  {
    const float4* p  = (const float4*)(dWih + (size_t)tid * NLAT);
    const float4* e4 = (const float4*)encs;
    float a = dBih[tid] + dBhh[tid];
#pragma unroll
    for (int r = 0; r < 16; ++r) {
      float4 wv = p[r]; float4 ev = e4[r];
      a = fmaf(ev.x, wv.x, a); a = fmaf(ev.y, wv.y, a);
      a = fmaf(ev.z, wv.z, a); a = fmaf(ev.w, wv.w, a);
    }
    gtmp[tid] = a;
  }
  __syncthreads();   // gtmp + zeroed hs visible
  float dinit[4];
#pragma unroll
  for (int g = 0; g < 4; ++g)
    dinit[g] = writer ? gtmp[g * NH + u] : 0.f;
  c = 0.f;

  // ============================ DECODER ============================
#pragma unroll 1
  for (int t = 0; t < NT; ++t) {
    const float4* hp = (const float4*)(hs + (t & 1) * NH + 32 * kc);
    float4 h0 = hp[0], h1 = hp[1], h2v = hp[2], h3 = hp[3];
    float zz[4];
#pragma unroll
    for (int g = 0; g < 4; ++g) {
      float A = dinit[g];
      A = dot2(dw[g * 16 +  0], bc2(h0.x), A);
      A = dot2(dw[g * 16 +  1], bc2(h0.y), A);
      A = dot2(dw[g * 16 +  2], bc2(h0.z), A);
      A = dot2(dw[g * 16 +  3], bc2(h0.w), A);
      A = dot2(dw[g * 16 +  4], bc2(h1.x), A);
      A = dot2(dw[g * 16 +  5], bc2(h1.y), A);
      A = dot2(dw[g * 16 +  6], bc2(h1.z), A);
      A = dot2(dw[g * 16 +  7], bc2(h1.w), A);
      A = dot2(dw[g * 16 +  8], bc2(h2v.x), A);
      A = dot2(dw[g * 16 +  9], bc2(h2v.y), A);
      A = dot2(dw[g * 16 + 10], bc2(h2v.z), A);
      A = dot2(dw[g * 16 + 11], bc2(h2v.w), A);
      A = dot2(dw[g * 16 + 12], bc2(h3.x), A);
      A = dot2(dw[g * 16 + 13], bc2(h3.y), A);
      A = dot2(dw[g * 16 + 14], bc2(h3.z), A);
      A = dot2(dw[g * 16 + 15], bc2(h3.w), A);
      A = qadd<QXOR1>(A);
      A = qadd<QXOR2>(A);
      zz[g] = A;
    }
    float zl = k0 ? zz[1] : zz[0];
    float zh = k0 ? zz[3] : zz[2];
    float z  = k1 ? zh : zl;
    float a  = fmaf(pa, __builtin_amdgcn_rcpf(1.f + __builtin_amdgcn_exp2f(z * km)), pb);
    float vf = dpp_mov<QP1>(a);
    float vg = dpp_mov<QP2>(a);
    float vo = dpp_mov<QP3>(a);
    c = fmaf(vf, c, a * vg);
    float h = vo * tanh_f(c);
    if (writer) {
      _Float16 hh = (_Float16)h;
      hs[((t + 1) & 1) * NH + u] = hh;
      hist[t * HSTR + u] = hh;
    }
    __syncthreads();
  }

  // ============ EPILOGUE: outD = hist @ dWl.T + dBl (R6-verified) ============
  {
    const int col = tid & 31, rg = tid >> 5;
    h2 wl[64];
    const float4* p0 = (const float4*)(dWl + (size_t)col * NH);
#pragma unroll
    for (int f = 0; f < 32; ++f) {
      float4 v = p0[f];
      wl[2 * f] = pk2(v.x, v.y); wl[2 * f + 1] = pk2(v.z, v.w);
    }
    const float bo = dBl[col];
    float* op = outD + (size_t)b * (NT * NDIN);
#pragma unroll 1
    for (int i = 0; i < 32; ++i) {
      int r = rg + 16 * i;
      const float4* hp = (const float4*)(hist + r * HSTR);
      float s = 0.f;
#pragma unroll
      for (int j = 0; j < 16; ++j) {
        float4 hvv = hp[j];
        s = dot2(wl[4 * j + 0], bc2(hvv.x), s);
        s = dot2(wl[4 * j + 1], bc2(hvv.y), s);
        s = dot2(wl[4 * j + 2], bc2(hvv.z), s);
        s = dot2(wl[4 * j + 3], bc2(hvv.w), s);
      }
      op[(size_t)r * NDIN + col] = s + bo;
    }
  }
}

#define SMEM_BYTES (NLAT * 4 + 2 * NH * 2 + NT * HSTR * 2 + 512 * 4)

extern "C" void kernel_launch(void* const* d_in, const int* in_sizes, int n_in,
                              void* d_out, int out_size, void* d_ws, size_t ws_size,
                              hipStream_t stream) {
  const float* x    = (const float*)d_in[0];
  const float* eWih = (const float*)d_in[1];
  const float* eWhh = (const float*)d_in[2];
  const float* eBih = (const float*)d_in[3];
  const float* eBhh = (const float*)d_in[4];
  const float* eWl  = (const float*)d_in[5];
  const float* eBl  = (const float*)d_in[6];
  const float* dWih = (const float*)d_in[7];
  const float* dWhh = (const float*)d_in[8];
  const float* dBih = (const float*)d_in[9];
  const float* dBhh = (const float*)d_in[10];
  const float* dWl  = (const float*)d_in[11];
  const float* dBl  = (const float*)d_in[12];

  float* outE = (float*)d_out;               // [256][64]
  float* outD = outE + (size_t)NB * NLAT;    // [256][512][32]

  (void)hipFuncSetAttribute((const void*)lstm_ae_kernel,
                            hipFuncAttributeMaxDynamicSharedMemorySize,
                            SMEM_BYTES);

  hipLaunchKernelGGL(lstm_ae_kernel, dim3(NB), dim3(512), SMEM_BYTES, stream,
                     x, eWih, eWhh, eBih, eBhh, eWl, eBl,
                     dWih, dWhh, dBih, dBhh, dWl, dBl, outE, outD);
}